// Round 14
// baseline (1715.567 us; speedup 1.0000x reference)
//
#include <hip/hip_runtime.h>

#define N_SERVICES 50000
#define N_PAD      50048   // 782*64
#define N_EDGES    1600000
#define N_CTX      6144    // BATCH*CONTEXT
#define EMB        32
#define BATCH      2048
#define FIN        128     // (CONTEXT+1)*EMB
#define N_TILES    782
#define BM         128
#define M_CHUNKS   16      // 2048 / BM
#define N_CHAINS   64
#define GEMM_BLKS  (M_CHUNKS * N_CHAINS)   // 1024
#define RUN_BASE   12      // 782 = 64*12 + 14 -> first 14 chains take 13 tiles
#define RUN_EXTRA  14
#define CE_BLKS    ((N_EDGES / 4 + 255) / 256)
#define REP_AGG    16      // DIAGNOSTIC: k_agg_tf repeats (idempotent)
#define REP_CNT    17      // DIAGNOSTIC: k_count_degi passes (net +1 via add/sub)

typedef __attribute__((ext_vector_type(4))) float f32x4;
typedef __attribute__((ext_vector_type(2))) float f32x2;
typedef __attribute__((ext_vector_type(8))) short short8;

__device__ inline unsigned short f2bf(float f) {
    unsigned u = __float_as_uint(f);
    unsigned r = (u + 0x7FFFu + ((u >> 16) & 1u)) >> 16;
    return (unsigned short)r;
}
__device__ inline float bf2f(unsigned short b) {
    return __uint_as_float(((unsigned)b) << 16);
}

// ---------------- degree count (int4; DIAGNOSTIC add/sub REP, net +1) ----------

__global__ void k_count_degi(const int* __restrict__ dst, int* __restrict__ degi) {
    int e4 = (blockIdx.x * 256 + threadIdx.x) * 4;
    if (e4 >= N_EDGES) return;
    int4 d = *(const int4*)(dst + e4);
#pragma unroll 1
    for (int p = 0; p < REP_CNT; ++p) {
        int delta = (p == 0) ? 1 : ((p & 1) ? 1 : -1);   // net across passes = +1
        atomicAdd(&degi[d.x], delta);
        atomicAdd(&degi[d.y], delta);
        atomicAdd(&degi[d.z], delta);
        atomicAdd(&degi[d.w], delta);
    }
}

// ---------------- scan pass 1; dis folded in ----------------

__global__ void k_scan_block(const int* __restrict__ degi, float* __restrict__ dis,
                             int* __restrict__ tmp, int* __restrict__ blocksum) {
    __shared__ int s[256];
    int t = threadIdx.x, i = blockIdx.x * 256 + t;
    int v = (i < N_SERVICES) ? degi[i] : 0;
    if (i < N_SERVICES) dis[i] = rsqrtf((float)(v + 1));  // +1 self-loop
    s[t] = v;
    __syncthreads();
#pragma unroll
    for (int o = 1; o < 256; o <<= 1) {
        int x = 0;
        if (t >= o) x = s[t - o];
        __syncthreads();
        if (t >= o) s[t] += x;
        __syncthreads();
    }
    if (i < N_SERVICES) tmp[i] = s[t] - v;       // exclusive within block
    if (t == 255) blocksum[blockIdx.x] = s[255];
}

// ---------------- fused: scan finish (+ctx list build)  ∥  layer-1 transform ----

__global__ __launch_bounds__(256) void k_scanfin_tf(
    const int* __restrict__ tmp, const int* __restrict__ blocksum,
    int* __restrict__ row_start, int* __restrict__ cursor,
    const int* __restrict__ ctx_idx, int* __restrict__ mask,
    int* __restrict__ ctx_list, int* __restrict__ ctx_count,
    const float* __restrict__ in, const float* __restrict__ W1,
    const float* __restrict__ dis, unsigned short* __restrict__ h) {
    __shared__ int s[256];
    __shared__ float Ws[EMB][EMB + 1];
    __shared__ float rows[8][EMB];
    int t = threadIdx.x;

    if (blockIdx.x < 196) {
        int v = (t < 196) ? blocksum[t] : 0;
        s[t] = v;
        __syncthreads();
#pragma unroll
        for (int o = 1; o < 256; o <<= 1) {
            int x = 0;
            if (t >= o) x = s[t - o];
            __syncthreads();
            if (t >= o) s[t] += x;
            __syncthreads();
        }
        int prefix = (blockIdx.x == 0) ? 0 : s[blockIdx.x - 1];
        int i = blockIdx.x * 256 + t;
        if (i < N_SERVICES) {
            int r = tmp[i] + prefix;
            row_start[i] = r;
            cursor[i] = r;
        }
        if (i < N_CTX) {
            int n = ctx_idx[i];
            if (atomicExch(&mask[n], 1) == 0)
                ctx_list[atomicAdd(ctx_count, 1)] = n;
        }
        if (i == 0) row_start[N_SERVICES] = N_EDGES;
    } else {
        int j = t & 31, li = t >> 5;
        for (int i = t; i < EMB * EMB; i += 256) Ws[i >> 5][i & 31] = W1[i];
        int node = (blockIdx.x - 196) * 8 + li;
        if (node < N_SERVICES) rows[li][j] = in[node * EMB + j];
        __syncthreads();
        if (node < N_SERVICES) {
            float acc = 0.f;
#pragma unroll
            for (int k = 0; k < EMB; ++k) acc = fmaf(rows[li][k], Ws[k][j], acc);
            h[node * EMB + j] = f2bf(acc * dis[node]);
        }
    }
}

// ---------------- CSR fill (int4: 4 edges/thread) ----------------

__global__ void k_fill(const int* __restrict__ src, const int* __restrict__ dst,
                       int* __restrict__ cursor, int* __restrict__ csr_src) {
    int e4 = (blockIdx.x * 256 + threadIdx.x) * 4;
    if (e4 < N_EDGES) {
        int4 s = *(const int4*)(src + e4);
        int4 d = *(const int4*)(dst + e4);
        csr_src[atomicAdd(&cursor[d.x], 1)] = s.x;
        csr_src[atomicAdd(&cursor[d.y], 1)] = s.y;
        csr_src[atomicAdd(&cursor[d.z], 1)] = s.z;
        csr_src[atomicAdd(&cursor[d.w], 1)] = s.w;
    }
}

// ---------------- fused layer-1 agg + ReLU + layer-2 transform (REP diag) -------

__global__ __launch_bounds__(256) void k_agg_tf(
    const int* __restrict__ row_start, const int* __restrict__ csr_src,
    const float* __restrict__ dis, const unsigned int* __restrict__ h2,
    const float* __restrict__ b, const float* __restrict__ W2,
    unsigned short* __restrict__ hout) {
    __shared__ float gr[16][33];
    __shared__ float Ws[32][33];
    int t = threadIdx.x;
    for (int i = t; i < EMB * EMB; i += 256) Ws[i >> 5][i & 31] = W2[i];

    int j2 = t & 15;                       // dim pair
    int local = t >> 4;
    int node = blockIdx.x * 16 + local;
    int e0 = row_start[node], e1 = row_start[node + 1];
    float dn = dis[node];

#pragma unroll 1
    for (int rep = 0; rep < REP_AGG; ++rep) {
        int e = e0;
        float al0 = 0.f, ah0 = 0.f, al1 = 0.f, ah1 = 0.f;
        float al2 = 0.f, ah2 = 0.f, al3 = 0.f, ah3 = 0.f;
        for (; e + 4 <= e1; e += 4) {
            int s0 = csr_src[e], s1 = csr_src[e + 1], s2 = csr_src[e + 2], s3 = csr_src[e + 3];
            unsigned v0 = h2[s0 * 16 + j2], v1 = h2[s1 * 16 + j2];
            unsigned v2 = h2[s2 * 16 + j2], v3 = h2[s3 * 16 + j2];
            al0 += bf2f((unsigned short)(v0 & 0xffff)); ah0 += bf2f((unsigned short)(v0 >> 16));
            al1 += bf2f((unsigned short)(v1 & 0xffff)); ah1 += bf2f((unsigned short)(v1 >> 16));
            al2 += bf2f((unsigned short)(v2 & 0xffff)); ah2 += bf2f((unsigned short)(v2 >> 16));
            al3 += bf2f((unsigned short)(v3 & 0xffff)); ah3 += bf2f((unsigned short)(v3 >> 16));
        }
        for (; e < e1; ++e) {
            unsigned v0 = h2[csr_src[e] * 16 + j2];
            al0 += bf2f((unsigned short)(v0 & 0xffff)); ah0 += bf2f((unsigned short)(v0 >> 16));
        }
        unsigned vn = h2[node * 16 + j2];
        float lo = dn * ((al0 + al1) + (al2 + al3) + bf2f((unsigned short)(vn & 0xffff))) + b[j2 * 2];
        float hi = dn * ((ah0 + ah1) + (ah2 + ah3) + bf2f((unsigned short)(vn >> 16))) + b[j2 * 2 + 1];
        gr[local][j2 * 2]     = fmaxf(lo, 0.f);
        gr[local][j2 * 2 + 1] = fmaxf(hi, 0.f);
        __syncthreads();

        // phase 2: transform the block's 16 g1 rows by W2; 2 nodes per thread
        int d = t & 31;
        int l0 = t >> 5;                   // 0..7
        float s0 = 0.f, s1 = 0.f;
#pragma unroll
        for (int k = 0; k < EMB; ++k) {
            float w = Ws[k][d];
            s0 = fmaf(gr[l0][k], w, s0);
            s1 = fmaf(gr[l0 + 8][k], w, s1);
        }
        int n0 = blockIdx.x * 16 + l0;
        hout[(size_t)n0 * EMB + d]       = f2bf(s0 * dis[n0]);
        hout[(size_t)(n0 + 8) * EMB + d] = f2bf(s1 * dis[n0 + 8]);
        __syncthreads();
    }
}

// ---------------- layer-2 agg over the compact ctx list ----------------

__global__ void k_agg_ctx(const int* __restrict__ row_start, const int* __restrict__ csr_src,
                          const float* __restrict__ dis, const unsigned int* __restrict__ h2,
                          const float* __restrict__ b, const int* __restrict__ ctx_list,
                          const int* __restrict__ ctx_count, float* __restrict__ out) {
    int t = threadIdx.x;
    int j2 = t & 15;
    int slot = blockIdx.x * 16 + (t >> 4);
    if (slot >= *ctx_count) return;
    int node = ctx_list[slot];
    int e = row_start[node], e1 = row_start[node + 1];
    float al0 = 0.f, ah0 = 0.f, al1 = 0.f, ah1 = 0.f;
    float al2 = 0.f, ah2 = 0.f, al3 = 0.f, ah3 = 0.f;
    for (; e + 4 <= e1; e += 4) {
        int s0 = csr_src[e], s1 = csr_src[e + 1], s2 = csr_src[e + 2], s3 = csr_src[e + 3];
        unsigned v0 = h2[s0 * 16 + j2], v1 = h2[s1 * 16 + j2];
        unsigned v2 = h2[s2 * 16 + j2], v3 = h2[s3 * 16 + j2];
        al0 += bf2f((unsigned short)(v0 & 0xffff)); ah0 += bf2f((unsigned short)(v0 >> 16));
        al1 += bf2f((unsigned short)(v1 & 0xffff)); ah1 += bf2f((unsigned short)(v1 >> 16));
        al2 += bf2f((unsigned short)(v2 & 0xffff)); ah2 += bf2f((unsigned short)(v2 >> 16));
        al3 += bf2f((unsigned short)(v3 & 0xffff)); ah3 += bf2f((unsigned short)(v3 >> 16));
    }
    for (; e < e1; ++e) {
        unsigned v0 = h2[csr_src[e] * 16 + j2];
        al0 += bf2f((unsigned short)(v0 & 0xffff)); ah0 += bf2f((unsigned short)(v0 >> 16));
    }
    float dn = dis[node];
    unsigned vn = h2[node * 16 + j2];
    float lo = dn * ((al0 + al1) + (al2 + al3) + bf2f((unsigned short)(vn & 0xffff))) + b[j2 * 2];
    float hi = dn * ((ah0 + ah1) + (ah2 + ah3) + bf2f((unsigned short)(vn >> 16))) + b[j2 * 2 + 1];
    f32x2 o; o.x = lo; o.y = hi;
    *(f32x2*)&out[node * EMB + j2 * 2] = o;
}

// ---------------- feature gather (emit bf16) ----------------

__global__ void k_gather(const int* __restrict__ user_idx, const int* __restrict__ ctx_idx,
                         const float* __restrict__ user_emb, const float* __restrict__ g2,
                         unsigned short* __restrict__ x) {
    int t = blockIdx.x * 256 + threadIdx.x;  // grid exact: BATCH*FIN
    int b = t >> 7, p = t & 127;
    float v;
    if (p < EMB) {
        v = user_emb[user_idx[b] * EMB + p];
    } else {
        int c = (p - EMB) >> 5, j = p & 31;
        v = g2[ctx_idx[b * 3 + c] * EMB + j];
    }
    x[t] = f2bf(v);
}

// ---------------- fc_W transpose+convert + zero degi/mask/ctx_count ----------------

__global__ __launch_bounds__(256) void k_cvtW(const float* __restrict__ W,
                                              short* __restrict__ Wt,
                                              int* __restrict__ degi,
                                              int* __restrict__ mask,
                                              int* __restrict__ ctx_count) {
    int gid = blockIdx.x * 256 + threadIdx.x;
    if (gid < N_SERVICES) { degi[gid] = 0; mask[gid] = 0; }
    if (gid == 0) *ctx_count = 0;

    __shared__ short lds[128][33];
    int t = threadIdx.x;
    int n0 = blockIdx.x * 32;
    int nx = t & 31;
    int n  = n0 + nx;
    int kg = t >> 5;                 // 0..7
#pragma unroll
    for (int r = 0; r < 16; ++r) {
        int k = r * 8 + kg;
        float v = (n < N_SERVICES) ? W[k * N_SERVICES + n] : 0.f;
        lds[k][nx] = (short)f2bf(v);
    }
    __syncthreads();
    int nr = t >> 3;                 // 0..31
    int kc = (t & 7) * 16;
    short tmp[16];
#pragma unroll
    for (int i = 0; i < 16; ++i) tmp[i] = lds[kc + i][nr];
    short8* dstp = (short8*)(Wt + (size_t)(n0 + nr) * FIN + kc);
    dstp[0] = *(short8*)&tmp[0];
    dstp[1] = *(short8*)&tmp[8];
}

// ---------------- final GEMM: r12-exact (dbuf LDS, NT stores) ----------------

__global__ __launch_bounds__(256, 2) void k_gemm3(
    const short* __restrict__ A, const short* __restrict__ Bt,
    const float* __restrict__ bias, float* __restrict__ out) {
    __shared__ float tile[2][BM][68];      // 2 x 34,816 B
    int t = threadIdx.x;
    int w = t >> 6;
    int l = t & 63;
    int lr = l & 15;
    int lg = l >> 4;
    int mc = blockIdx.x >> 6;
    int c  = blockIdx.x & (N_CHAINS - 1);
    int nt0 = c * RUN_BASE + (c < RUN_EXTRA ? c : RUN_EXTRA);
    int cnt = RUN_BASE + (c < RUN_EXTRA ? 1 : 0);
    int m_base = mc * BM;

    short8 a[8][4];
#pragma unroll
    for (int mi = 0; mi < 8; ++mi) {
        const short* arow = A + (size_t)(m_base + mi * 16 + lr) * FIN + lg * 8;
#pragma unroll
        for (int ks = 0; ks < 4; ++ks) a[mi][ks] = *(const short8*)(arow + ks * 32);
    }

    const short* bbase = Bt + (size_t)(w * 16 + lr) * FIN + lg * 8;
    short8 b0[4], b1[4];
    {
        const short* p = bbase + (size_t)nt0 * 64 * FIN;
#pragma unroll
        for (int ks = 0; ks < 4; ++ks) b0[ks] = *(const short8*)(p + ks * 32);
    }

    int scol = lr * 4;
    int p = 0;

    for (int i = 0; i < cnt; ++i) {
        int nt = nt0 + i;
        if (i + 1 < cnt) {
            const short* pp = bbase + (size_t)(nt + 1) * 64 * FIN;
#pragma unroll
            for (int ks = 0; ks < 4; ++ks) b1[ks] = *(const short8*)(pp + ks * 32);
        }
#pragma unroll
        for (int mi = 0; mi < 8; ++mi) {
            f32x4 acc = {};
#pragma unroll
            for (int ks = 0; ks < 4; ++ks)
                acc = __builtin_amdgcn_mfma_f32_16x16x32_bf16(b0[ks], a[mi][ks], acc, 0, 0, 0);
            *(f32x4*)&tile[p][mi * 16 + lr][w * 16 + lg * 4] = acc;
        }
        __syncthreads();                   // single barrier per iteration
        {
            int gcol = nt * 64 + scol;
            bool ok = gcol < N_SERVICES;
            f32x4 bv = {};
            if (ok) bv = *(const f32x4*)&bias[gcol];
            float* ob = out + (size_t)m_base * N_SERVICES + gcol;
#pragma unroll
            for (int si = 0; si < 8; ++si) {
                int row = w * 32 + si * 4 + lg;
                f32x4 v = *(const f32x4*)&tile[p][row][scol] + bv;
                if (ok)
                    __builtin_nontemporal_store(
                        v, (f32x4*)(ob + (size_t)row * N_SERVICES));
            }
        }
        p ^= 1;
#pragma unroll
        for (int ks = 0; ks < 4; ++ks) b0[ks] = b1[ks];
    }
}

// ---------------- launch ----------------

extern "C" void kernel_launch(void* const* d_in, const int* in_sizes, int n_in,
                              void* d_out, int out_size, void* d_ws, size_t ws_size,
                              hipStream_t stream) {
    const int*   user_idx    = (const int*)d_in[0];
    const int*   ctx_idx     = (const int*)d_in[1];
    const int*   ei          = (const int*)d_in[2];
    const float* user_emb    = (const float*)d_in[3];
    const float* service_emb = (const float*)d_in[4];
    const float* W1          = (const float*)d_in[5];
    const float* b1          = (const float*)d_in[6];
    const float* W2          = (const float*)d_in[7];
    const float* b2          = (const float*)d_in[8];
    const float* fcW         = (const float*)d_in[9];
    const float* fcb         = (const float*)d_in[10];
    float* out = (float*)d_out;

    const int* src = ei;
    const int* dst = ei + N_EDGES;

    char* ws = (char*)d_ws;
    float*          dis       = (float*)(ws);                    // 200,000
    unsigned short* h1        = (unsigned short*)(ws + 200000);  // 3,200,000 (bf16 h1')
    unsigned short* h2b       = (unsigned short*)(ws + 3400000); // 3,200,000 (bf16 h2')
    float*          g         = (float*)(ws + 6600000);          // 6,400,000 (g2, ctx rows only)
    unsigned short* xb        = (unsigned short*)(ws + 13000000);//   524,288
    int*            degi      = (int*)(ws + 13000000);           // 200,000 overlay (dead before k_gather)
    short*          Wt        = (short*)(ws + 13524288);         // 12,812,288
    int*            row_start = (int*)(ws + 26336576);           // 200,004
    int*            cursor    = (int*)(ws + 26536580);           // 200,000
    int*            csr_src   = (int*)(ws + 26736580);           // 6,400,000
    int*            tmp       = (int*)(ws + 26736580);           // 200,000 overlay (dead before k_fill)
    int*            blocksum  = (int*)(ws + 33136580);           // 1,024
    int*            mask      = (int*)(ws + 33137604);           // 200,000
    int*            ctx_list  = (int*)(ws + 33337604);           // 24,576
    int*            ctx_count = (int*)(ws + 33362180);           // 4     (total ~33.4 MB)

    // cvtW also zeroes degi + mask + ctx_count (runs first)
    k_cvtW<<<N_PAD / 32, 256, 0, stream>>>(fcW, Wt, degi, mask, ctx_count);

    // CSR build (count_degi REP-instrumented this round)
    k_count_degi<<<CE_BLKS, 256, 0, stream>>>(dst, degi);
    k_scan_block<<<196, 256, 0, stream>>>(degi, dis, tmp, blocksum);
    k_scanfin_tf<<<196 + 6250, 256, 0, stream>>>(tmp, blocksum, row_start, cursor,
                                                 ctx_idx, mask, ctx_list, ctx_count,
                                                 service_emb, W1, dis, h1);
    k_fill<<<CE_BLKS, 256, 0, stream>>>(src, dst, cursor, csr_src);

    // fused layer-1 agg + ReLU + layer-2 transform (REP-instrumented this round)
    k_agg_tf<<<3125, 256, 0, stream>>>(row_start, csr_src, dis,
                                       (const unsigned int*)h1, b1, W2, h2b);
    // layer-2 agg over compact ctx list
    k_agg_ctx<<<N_CTX / 16, 256, 0, stream>>>(row_start, csr_src, dis,
                                              (const unsigned int*)h2b, b2,
                                              ctx_list, ctx_count, g);

    k_gather<<<BATCH * FIN / 256, 256, 0, stream>>>(user_idx, ctx_idx, user_emb, g, xb);

    k_gemm3<<<GEMM_BLKS, 256, 0, stream>>>((const short*)xb, Wt, fcb, out);
}

// Round 15
// 274.542 us; speedup vs baseline: 6.2488x; 6.2488x over previous
//
#include <hip/hip_runtime.h>

#define N_SERVICES 50000
#define N_PAD      50048   // 782*64
#define N_EDGES    1600000
#define N_CTX      6144    // BATCH*CONTEXT
#define EMB        32
#define BATCH      2048
#define FIN        128     // (CONTEXT+1)*EMB
#define N_TILES    782
#define BM         128
#define M_CHUNKS   16      // 2048 / BM
#define N_CHAINS   64
#define GEMM_BLKS  (M_CHUNKS * N_CHAINS)   // 1024
#define RUN_BASE   12      // 782 = 64*12 + 14
#define RUN_EXTRA  14

// --- tiled CSR build geometry ---
#define RANGE      8192            // nodes per range (2^13)
#define R_RANGES   7               // ceil(50000/8192)
#define PSTRIDE    (R_RANGES * RANGE)  // 57344 (padded node stride)
#define C_CHUNKS   16
#define EPC        (N_EDGES / C_CHUNKS)   // 100000 edges/chunk
#define I4PC       (EPC / 4)              // 25000 int4/chunk

typedef __attribute__((ext_vector_type(4))) float f32x4;
typedef __attribute__((ext_vector_type(2))) float f32x2;
typedef __attribute__((ext_vector_type(8))) short short8;

__device__ inline unsigned short f2bf(float f) {
    unsigned u = __float_as_uint(f);
    unsigned r = (u + 0x7FFFu + ((u >> 16) & 1u)) >> 16;
    return (unsigned short)r;
}
__device__ inline float bf2f(unsigned short b) {
    return __uint_as_float(((unsigned)b) << 16);
}

// ---------------- tiled count: LDS histogram, NO global atomics ----------------
// grid R_RANGES*C_CHUNKS = 112. block (r,c): histogram chunk c over node range r.

__global__ __launch_bounds__(256) void k_tiled_count(const int* __restrict__ dst,
                                                     unsigned short* __restrict__ partial) {
    __shared__ int hist[RANGE];
    int t = threadIdx.x;
    int r = blockIdx.x / C_CHUNKS;
    int c = blockIdx.x % C_CHUNKS;
    for (int i = t; i < RANGE; i += 256) hist[i] = 0;
    __syncthreads();
    const int4* d4 = (const int4*)(dst + c * EPC);
    for (int i = t; i < I4PC; i += 256) {
        int4 d = d4[i];
        if ((d.x >> 13) == r) atomicAdd(&hist[d.x & (RANGE - 1)], 1);
        if ((d.y >> 13) == r) atomicAdd(&hist[d.y & (RANGE - 1)], 1);
        if ((d.z >> 13) == r) atomicAdd(&hist[d.z & (RANGE - 1)], 1);
        if ((d.w >> 13) == r) atomicAdd(&hist[d.w & (RANGE - 1)], 1);
    }
    __syncthreads();
    unsigned short* p = partial + (size_t)c * PSTRIDE + r * RANGE;
    for (int i = t; i < RANGE; i += 256) p[i] = (unsigned short)hist[i];
}

// ---------------- scan pass 1; chunk-reduce + dis folded in ----------------

__global__ void k_scan_block(const unsigned short* __restrict__ partial,
                             float* __restrict__ dis,
                             int* __restrict__ tmp, int* __restrict__ blocksum) {
    __shared__ int s[256];
    int t = threadIdx.x, i = blockIdx.x * 256 + t;
    int v = 0;
    if (i < N_SERVICES) {
#pragma unroll
        for (int c = 0; c < C_CHUNKS; ++c) v += partial[(size_t)c * PSTRIDE + i];
        dis[i] = rsqrtf((float)(v + 1));  // +1 self-loop
    }
    s[t] = v;
    __syncthreads();
#pragma unroll
    for (int o = 1; o < 256; o <<= 1) {
        int x = 0;
        if (t >= o) x = s[t - o];
        __syncthreads();
        if (t >= o) s[t] += x;
        __syncthreads();
    }
    if (i < N_SERVICES) tmp[i] = s[t] - v;       // exclusive within block
    if (t == 255) blocksum[blockIdx.x] = s[255];
}

// ---------------- fused: scan finish (+ctx list build)  ∥  layer-1 transform ----

__global__ __launch_bounds__(256) void k_scanfin_tf(
    const int* __restrict__ tmp, const int* __restrict__ blocksum,
    int* __restrict__ row_start,
    const int* __restrict__ ctx_idx, int* __restrict__ mask,
    int* __restrict__ ctx_list, int* __restrict__ ctx_count,
    const float* __restrict__ in, const float* __restrict__ W1,
    const float* __restrict__ dis, unsigned short* __restrict__ h) {
    __shared__ int s[256];
    __shared__ float Ws[EMB][EMB + 1];
    __shared__ float rows[8][EMB];
    int t = threadIdx.x;

    if (blockIdx.x < 196) {
        int v = (t < 196) ? blocksum[t] : 0;
        s[t] = v;
        __syncthreads();
#pragma unroll
        for (int o = 1; o < 256; o <<= 1) {
            int x = 0;
            if (t >= o) x = s[t - o];
            __syncthreads();
            if (t >= o) s[t] += x;
            __syncthreads();
        }
        int prefix = (blockIdx.x == 0) ? 0 : s[blockIdx.x - 1];
        int i = blockIdx.x * 256 + t;
        if (i < N_SERVICES) row_start[i] = tmp[i] + prefix;
        if (i < N_CTX) {
            int n = ctx_idx[i];
            if (atomicExch(&mask[n], 1) == 0)
                ctx_list[atomicAdd(ctx_count, 1)] = n;
        }
        if (i == 0) row_start[N_SERVICES] = N_EDGES;
    } else {
        int j = t & 31, li = t >> 5;
        for (int i = t; i < EMB * EMB; i += 256) Ws[i >> 5][i & 31] = W1[i];
        int node = (blockIdx.x - 196) * 8 + li;
        if (node < N_SERVICES) rows[li][j] = in[node * EMB + j];
        __syncthreads();
        if (node < N_SERVICES) {
            float acc = 0.f;
#pragma unroll
            for (int k = 0; k < EMB; ++k) acc = fmaf(rows[li][k], Ws[k][j], acc);
            h[node * EMB + j] = f2bf(acc * dis[node]);
        }
    }
}

// ---------------- per-chunk absolute cursors (prefix over chunks) ----------------

__global__ void k_cursor(const int* __restrict__ row_start,
                         const unsigned short* __restrict__ partial,
                         int* __restrict__ cursor_int) {
    int i = blockIdx.x * 256 + threadIdx.x;
    if (i >= N_SERVICES) return;
    int s = row_start[i];
#pragma unroll
    for (int c = 0; c < C_CHUNKS; ++c) {
        int cnt = partial[(size_t)c * PSTRIDE + i];
        cursor_int[(size_t)c * PSTRIDE + i] = s;
        s += cnt;
    }
}

// ---------------- fill: LDS cursors, NO global atomics ----------------

__global__ __launch_bounds__(256) void k_fill(const int* __restrict__ src,
                                              const int* __restrict__ dst,
                                              const int* __restrict__ cursor_int,
                                              int* __restrict__ csr_src) {
    __shared__ int cur[RANGE];
    int t = threadIdx.x;
    int r = blockIdx.x / C_CHUNKS;
    int c = blockIdx.x % C_CHUNKS;
    const int* cbase = cursor_int + (size_t)c * PSTRIDE + r * RANGE;
    for (int i = t; i < RANGE; i += 256) cur[i] = cbase[i];
    __syncthreads();
    const int4* d4 = (const int4*)(dst + c * EPC);
    const int4* s4 = (const int4*)(src + c * EPC);
    for (int i = t; i < I4PC; i += 256) {
        int4 d = d4[i];
        int4 s = s4[i];
        if ((d.x >> 13) == r) csr_src[atomicAdd(&cur[d.x & (RANGE - 1)], 1)] = s.x;
        if ((d.y >> 13) == r) csr_src[atomicAdd(&cur[d.y & (RANGE - 1)], 1)] = s.y;
        if ((d.z >> 13) == r) csr_src[atomicAdd(&cur[d.z & (RANGE - 1)], 1)] = s.z;
        if ((d.w >> 13) == r) csr_src[atomicAdd(&cur[d.w & (RANGE - 1)], 1)] = s.w;
    }
}

// ---------------- fused layer-1 agg + ReLU + layer-2 transform ----------------

__global__ __launch_bounds__(256) void k_agg_tf(
    const int* __restrict__ row_start, const int* __restrict__ csr_src,
    const float* __restrict__ dis, const unsigned int* __restrict__ h2,
    const float* __restrict__ b, const float* __restrict__ W2,
    unsigned short* __restrict__ hout) {
    __shared__ float gr[16][33];
    __shared__ float Ws[32][33];
    int t = threadIdx.x;
    for (int i = t; i < EMB * EMB; i += 256) Ws[i >> 5][i & 31] = W2[i];

    int j2 = t & 15;                       // dim pair
    int local = t >> 4;
    int node = blockIdx.x * 16 + local;
    int e = row_start[node], e1 = row_start[node + 1];
    float al0 = 0.f, ah0 = 0.f, al1 = 0.f, ah1 = 0.f;
    float al2 = 0.f, ah2 = 0.f, al3 = 0.f, ah3 = 0.f;
    for (; e + 4 <= e1; e += 4) {
        int s0 = csr_src[e], s1 = csr_src[e + 1], s2 = csr_src[e + 2], s3 = csr_src[e + 3];
        unsigned v0 = h2[s0 * 16 + j2], v1 = h2[s1 * 16 + j2];
        unsigned v2 = h2[s2 * 16 + j2], v3 = h2[s3 * 16 + j2];
        al0 += bf2f((unsigned short)(v0 & 0xffff)); ah0 += bf2f((unsigned short)(v0 >> 16));
        al1 += bf2f((unsigned short)(v1 & 0xffff)); ah1 += bf2f((unsigned short)(v1 >> 16));
        al2 += bf2f((unsigned short)(v2 & 0xffff)); ah2 += bf2f((unsigned short)(v2 >> 16));
        al3 += bf2f((unsigned short)(v3 & 0xffff)); ah3 += bf2f((unsigned short)(v3 >> 16));
    }
    for (; e < e1; ++e) {
        unsigned v0 = h2[csr_src[e] * 16 + j2];
        al0 += bf2f((unsigned short)(v0 & 0xffff)); ah0 += bf2f((unsigned short)(v0 >> 16));
    }
    float dn = dis[node];
    unsigned vn = h2[node * 16 + j2];
    float lo = dn * ((al0 + al1) + (al2 + al3) + bf2f((unsigned short)(vn & 0xffff))) + b[j2 * 2];
    float hi = dn * ((ah0 + ah1) + (ah2 + ah3) + bf2f((unsigned short)(vn >> 16))) + b[j2 * 2 + 1];
    gr[local][j2 * 2]     = fmaxf(lo, 0.f);
    gr[local][j2 * 2 + 1] = fmaxf(hi, 0.f);
    __syncthreads();

    int d = t & 31;
    int l0 = t >> 5;                       // 0..7
    float s0 = 0.f, s1 = 0.f;
#pragma unroll
    for (int k = 0; k < EMB; ++k) {
        float w = Ws[k][d];
        s0 = fmaf(gr[l0][k], w, s0);
        s1 = fmaf(gr[l0 + 8][k], w, s1);
    }
    int n0 = blockIdx.x * 16 + l0;
    hout[(size_t)n0 * EMB + d]       = f2bf(s0 * dis[n0]);
    hout[(size_t)(n0 + 8) * EMB + d] = f2bf(s1 * dis[n0 + 8]);
}

// ---------------- layer-2 agg over the compact ctx list ----------------

__global__ void k_agg_ctx(const int* __restrict__ row_start, const int* __restrict__ csr_src,
                          const float* __restrict__ dis, const unsigned int* __restrict__ h2,
                          const float* __restrict__ b, const int* __restrict__ ctx_list,
                          const int* __restrict__ ctx_count, float* __restrict__ out) {
    int t = threadIdx.x;
    int j2 = t & 15;
    int slot = blockIdx.x * 16 + (t >> 4);
    if (slot >= *ctx_count) return;
    int node = ctx_list[slot];
    int e = row_start[node], e1 = row_start[node + 1];
    float al0 = 0.f, ah0 = 0.f, al1 = 0.f, ah1 = 0.f;
    float al2 = 0.f, ah2 = 0.f, al3 = 0.f, ah3 = 0.f;
    for (; e + 4 <= e1; e += 4) {
        int s0 = csr_src[e], s1 = csr_src[e + 1], s2 = csr_src[e + 2], s3 = csr_src[e + 3];
        unsigned v0 = h2[s0 * 16 + j2], v1 = h2[s1 * 16 + j2];
        unsigned v2 = h2[s2 * 16 + j2], v3 = h2[s3 * 16 + j2];
        al0 += bf2f((unsigned short)(v0 & 0xffff)); ah0 += bf2f((unsigned short)(v0 >> 16));
        al1 += bf2f((unsigned short)(v1 & 0xffff)); ah1 += bf2f((unsigned short)(v1 >> 16));
        al2 += bf2f((unsigned short)(v2 & 0xffff)); ah2 += bf2f((unsigned short)(v2 >> 16));
        al3 += bf2f((unsigned short)(v3 & 0xffff)); ah3 += bf2f((unsigned short)(v3 >> 16));
    }
    for (; e < e1; ++e) {
        unsigned v0 = h2[csr_src[e] * 16 + j2];
        al0 += bf2f((unsigned short)(v0 & 0xffff)); ah0 += bf2f((unsigned short)(v0 >> 16));
    }
    float dn = dis[node];
    unsigned vn = h2[node * 16 + j2];
    float lo = dn * ((al0 + al1) + (al2 + al3) + bf2f((unsigned short)(vn & 0xffff))) + b[j2 * 2];
    float hi = dn * ((ah0 + ah1) + (ah2 + ah3) + bf2f((unsigned short)(vn >> 16))) + b[j2 * 2 + 1];
    f32x2 o; o.x = lo; o.y = hi;
    *(f32x2*)&out[node * EMB + j2 * 2] = o;
}

// ---------------- feature gather (emit bf16) ----------------

__global__ void k_gather(const int* __restrict__ user_idx, const int* __restrict__ ctx_idx,
                         const float* __restrict__ user_emb, const float* __restrict__ g2,
                         unsigned short* __restrict__ x) {
    int t = blockIdx.x * 256 + threadIdx.x;  // grid exact: BATCH*FIN
    int b = t >> 7, p = t & 127;
    float v;
    if (p < EMB) {
        v = user_emb[user_idx[b] * EMB + p];
    } else {
        int c = (p - EMB) >> 5, j = p & 31;
        v = g2[ctx_idx[b * 3 + c] * EMB + j];
    }
    x[t] = f2bf(v);
}

// ---------------- fc_W transpose+convert + zero mask/ctx_count ----------------

__global__ __launch_bounds__(256) void k_cvtW(const float* __restrict__ W,
                                              short* __restrict__ Wt,
                                              int* __restrict__ mask,
                                              int* __restrict__ ctx_count) {
    int gid = blockIdx.x * 256 + threadIdx.x;
    if (gid < N_SERVICES) mask[gid] = 0;
    if (gid == 0) *ctx_count = 0;

    __shared__ short lds[128][33];
    int t = threadIdx.x;
    int n0 = blockIdx.x * 32;
    int nx = t & 31;
    int n  = n0 + nx;
    int kg = t >> 5;                 // 0..7
#pragma unroll
    for (int r = 0; r < 16; ++r) {
        int k = r * 8 + kg;
        float v = (n < N_SERVICES) ? W[k * N_SERVICES + n] : 0.f;
        lds[k][nx] = (short)f2bf(v);
    }
    __syncthreads();
    int nr = t >> 3;                 // 0..31
    int kc = (t & 7) * 16;
    short tmp[16];
#pragma unroll
    for (int i = 0; i < 16; ++i) tmp[i] = lds[kc + i][nr];
    short8* dstp = (short8*)(Wt + (size_t)(n0 + nr) * FIN + kc);
    dstp[0] = *(short8*)&tmp[0];
    dstp[1] = *(short8*)&tmp[8];
}

// ---------------- final GEMM: r12-exact (dbuf LDS, NT stores) ----------------

__global__ __launch_bounds__(256, 2) void k_gemm3(
    const short* __restrict__ A, const short* __restrict__ Bt,
    const float* __restrict__ bias, float* __restrict__ out) {
    __shared__ float tile[2][BM][68];      // 2 x 34,816 B
    int t = threadIdx.x;
    int w = t >> 6;
    int l = t & 63;
    int lr = l & 15;
    int lg = l >> 4;
    int mc = blockIdx.x >> 6;
    int c  = blockIdx.x & (N_CHAINS - 1);
    int nt0 = c * RUN_BASE + (c < RUN_EXTRA ? c : RUN_EXTRA);
    int cnt = RUN_BASE + (c < RUN_EXTRA ? 1 : 0);
    int m_base = mc * BM;

    short8 a[8][4];
#pragma unroll
    for (int mi = 0; mi < 8; ++mi) {
        const short* arow = A + (size_t)(m_base + mi * 16 + lr) * FIN + lg * 8;
#pragma unroll
        for (int ks = 0; ks < 4; ++ks) a[mi][ks] = *(const short8*)(arow + ks * 32);
    }

    const short* bbase = Bt + (size_t)(w * 16 + lr) * FIN + lg * 8;
    short8 b0[4], b1[4];
    {
        const short* p = bbase + (size_t)nt0 * 64 * FIN;
#pragma unroll
        for (int ks = 0; ks < 4; ++ks) b0[ks] = *(const short8*)(p + ks * 32);
    }

    int scol = lr * 4;
    int p = 0;

    for (int i = 0; i < cnt; ++i) {
        int nt = nt0 + i;
        if (i + 1 < cnt) {
            const short* pp = bbase + (size_t)(nt + 1) * 64 * FIN;
#pragma unroll
            for (int ks = 0; ks < 4; ++ks) b1[ks] = *(const short8*)(pp + ks * 32);
        }
#pragma unroll
        for (int mi = 0; mi < 8; ++mi) {
            f32x4 acc = {};
#pragma unroll
            for (int ks = 0; ks < 4; ++ks)
                acc = __builtin_amdgcn_mfma_f32_16x16x32_bf16(b0[ks], a[mi][ks], acc, 0, 0, 0);
            *(f32x4*)&tile[p][mi * 16 + lr][w * 16 + lg * 4] = acc;
        }
        __syncthreads();                   // single barrier per iteration
        {
            int gcol = nt * 64 + scol;
            bool ok = gcol < N_SERVICES;
            f32x4 bv = {};
            if (ok) bv = *(const f32x4*)&bias[gcol];
            float* ob = out + (size_t)m_base * N_SERVICES + gcol;
#pragma unroll
            for (int si = 0; si < 8; ++si) {
                int row = w * 32 + si * 4 + lg;
                f32x4 v = *(const f32x4*)&tile[p][row][scol] + bv;
                if (ok)
                    __builtin_nontemporal_store(
                        v, (f32x4*)(ob + (size_t)row * N_SERVICES));
            }
        }
        p ^= 1;
#pragma unroll
        for (int ks = 0; ks < 4; ++ks) b0[ks] = b1[ks];
    }
}

// ---------------- launch ----------------

extern "C" void kernel_launch(void* const* d_in, const int* in_sizes, int n_in,
                              void* d_out, int out_size, void* d_ws, size_t ws_size,
                              hipStream_t stream) {
    const int*   user_idx    = (const int*)d_in[0];
    const int*   ctx_idx     = (const int*)d_in[1];
    const int*   ei          = (const int*)d_in[2];
    const float* user_emb    = (const float*)d_in[3];
    const float* service_emb = (const float*)d_in[4];
    const float* W1          = (const float*)d_in[5];
    const float* b1          = (const float*)d_in[6];
    const float* W2          = (const float*)d_in[7];
    const float* b2          = (const float*)d_in[8];
    const float* fcW         = (const float*)d_in[9];
    const float* fcb         = (const float*)d_in[10];
    float* out = (float*)d_out;

    const int* src = ei;
    const int* dst = ei + N_EDGES;

    char* ws = (char*)d_ws;
    float*          dis        = (float*)(ws);                    // 200,000
    unsigned short* h1         = (unsigned short*)(ws + 200000);  // 3,200,000 (bf16 h1')
    unsigned short* h2b        = (unsigned short*)(ws + 3400000); // 3,200,000 (bf16 h2')
    float*          g          = (float*)(ws + 6600000);          // 6,400,000 (g2, ctx rows)
    int*            cursor_int = (int*)(ws + 6600000);            // 3,670,016 overlay (dead before k_agg_ctx)
    unsigned short* xb         = (unsigned short*)(ws + 13000000);//   524,288
    short*          Wt         = (short*)(ws + 13524288);         // 12,812,288
    int*            row_start  = (int*)(ws + 26336576);           // 200,004
    int*            csr_src    = (int*)(ws + 26736580);           // 6,400,000
    int*            tmp        = (int*)(ws + 26736580);           // 200,000 overlay (dead before k_fill)
    int*            blocksum   = (int*)(ws + 33136580);           // 1,024
    int*            mask       = (int*)(ws + 33137604);           // 200,000
    int*            ctx_list   = (int*)(ws + 33337604);           // 24,576
    int*            ctx_count  = (int*)(ws + 33362180);           // 4
    unsigned short* partial    = (unsigned short*)(ws + 33362192);// 1,835,008 (total ~35.2 MB)

    // cvtW also zeroes mask + ctx_count (runs first)
    k_cvtW<<<N_PAD / 32, 256, 0, stream>>>(fcW, Wt, mask, ctx_count);

    // CSR build — no global atomics
    k_tiled_count<<<R_RANGES * C_CHUNKS, 256, 0, stream>>>(dst, partial);
    k_scan_block<<<196, 256, 0, stream>>>(partial, dis, tmp, blocksum);
    k_scanfin_tf<<<196 + 6250, 256, 0, stream>>>(tmp, blocksum, row_start,
                                                 ctx_idx, mask, ctx_list, ctx_count,
                                                 service_emb, W1, dis, h1);
    k_cursor<<<196, 256, 0, stream>>>(row_start, partial, cursor_int);
    k_fill<<<R_RANGES * C_CHUNKS, 256, 0, stream>>>(src, dst, cursor_int, csr_src);

    // fused layer-1 agg + ReLU + layer-2 transform (g1 never leaves LDS)
    k_agg_tf<<<3125, 256, 0, stream>>>(row_start, csr_src, dis,
                                       (const unsigned int*)h1, b1, W2, h2b);
    // layer-2 agg over compact ctx list (overwrites cursor_int region — dead)
    k_agg_ctx<<<N_CTX / 16, 256, 0, stream>>>(row_start, csr_src, dis,
                                              (const unsigned int*)h2b, b2,
                                              ctx_list, ctx_count, g);

    k_gather<<<BATCH * FIN / 256, 256, 0, stream>>>(user_idx, ctx_idx, user_emb, g, xb);

    k_gemm3<<<GEMM_BLKS, 256, 0, stream>>>((const short*)xb, Wt, fcb, out);
}